// Round 2
// baseline (941.946 us; speedup 1.0000x reference)
//
#include <hip/hip_runtime.h>

// out[n,:] = ci[n] * sum_{e: dst[e]==n} sigmoid(<review_feat[e,:], ps_w>) * cj[src[e]] * weight[src[e],:]
//
// Round-1 lesson: edge-scatter f32 atomics are atomic-op-rate bound
// (204.8M atomics ~= 301G/s = L2 ceiling; WRITE_SIZE 800MB). This version
// builds a dst-CSR on device each call (deterministic, capture-safe):
//   k1: gate + degree histogram   (streams review_feat, the 819MB floor)
//   k2: exclusive scan of degrees (single 1024-thread block)
//   k3: scatter (src,scale) pairs into CSR order (3.2M small atomics)
//   k4: node-parallel gather-reduce, one coalesced row store, NO out atomics
// Falls back to the round-1 atomic kernel if ws_size is too small.

// ---------------- k1: per-edge gate + degree histogram ----------------
__global__ __launch_bounds__(256) void k1_gate_hist(
    const float* __restrict__ review_feat,  // [E,64]
    const float* __restrict__ ps_w,         // [64]
    const float* __restrict__ cj,           // [N]
    const float* __restrict__ ci,           // [N]
    const int*   __restrict__ src,          // [E]
    const int*   __restrict__ dst,          // [E]
    float*       __restrict__ scale,        // [E] out
    unsigned*    __restrict__ deg,          // [N] out (pre-zeroed)
    int E)
{
    const int lane  = threadIdx.x & 63;
    const int wib   = threadIdx.x >> 6;
    const int group = lane >> 4;   // which of the wave's 4 edges
    const int sub   = lane & 15;   // float4 chunk within the 64-row
    const float4 pw = *reinterpret_cast<const float4*>(ps_w + sub * 4);

    const long long nwaves = (long long)gridDim.x * 4;
    for (long long w = (long long)blockIdx.x * 4 + wib; w * 4 < E; w += nwaves) {
        const long long e = w * 4 + group;
        float x = 0.f;
        if (e < E) {
            const float4 rv = *reinterpret_cast<const float4*>(review_feat + e * 64 + sub * 4);
            x = rv.x * pw.x + rv.y * pw.y + rv.z * pw.z + rv.w * pw.w;
        }
        // 16-lane butterfly (stays within the group)
        x += __shfl_xor(x, 1);
        x += __shfl_xor(x, 2);
        x += __shfl_xor(x, 4);
        x += __shfl_xor(x, 8);
        if (sub == 0 && e < E) {
            const int s = src[e];
            const int d = dst[e];
            const float gate = 1.f / (1.f + __expf(-x));
            scale[e] = gate * cj[s] * ci[d];   // fold ci[dst] in here
            atomicAdd(&deg[d], 1u);
        }
    }
}

// ---------------- k2: exclusive scan (single block) ----------------
__global__ __launch_bounds__(1024) void k2_scan(
    const unsigned* __restrict__ deg,     // [N]
    unsigned*       __restrict__ offs,    // [N+1] out
    unsigned*       __restrict__ cursor,  // [N]   out (copy of offs)
    int N, int E)
{
    __shared__ unsigned sm[1024];
    const int t = threadIdx.x;
    const int C = (N + 1023) >> 10;       // elems per thread
    const int base = t * C;

    unsigned sum = 0;
    for (int i = 0; i < C; ++i) {
        const int idx = base + i;
        if (idx < N) sum += deg[idx];
    }
    sm[t] = sum;
    __syncthreads();
    for (int off = 1; off < 1024; off <<= 1) {
        const unsigned v = (t >= off) ? sm[t - off] : 0u;
        __syncthreads();
        sm[t] += v;
        __syncthreads();
    }
    unsigned run = sm[t] - sum;           // exclusive prefix of this chunk
    for (int i = 0; i < C; ++i) {
        const int idx = base + i;
        if (idx < N) {
            const unsigned d = deg[idx];
            offs[idx]   = run;
            cursor[idx] = run;
            run += d;
        }
    }
    if (t == 0) offs[N] = (unsigned)E;
}

// ---------------- k3: scatter (src,scale) pairs into CSR order ----------------
__global__ __launch_bounds__(256) void k3_scatter(
    const int*   __restrict__ src,
    const int*   __restrict__ dst,
    const float* __restrict__ scale,
    unsigned*    __restrict__ cursor,
    int2*        __restrict__ pairs,      // [E] (src, scale-bits)
    int E)
{
    const long long stride = (long long)gridDim.x * blockDim.x;
    for (long long e = (long long)blockIdx.x * blockDim.x + threadIdx.x; e < E; e += stride) {
        const int d = dst[e];
        const unsigned pos = atomicAdd(&cursor[d], 1u);
        pairs[pos] = make_int2(src[e], __float_as_int(scale[e]));
    }
}

// ---------------- k4: node-parallel gather-reduce ----------------
__global__ __launch_bounds__(256) void k4_gather(
    const float*    __restrict__ weight,  // [N,64]
    const unsigned* __restrict__ offs,    // [N+1]
    const int2*     __restrict__ pairs,   // [E]
    float*          __restrict__ out,     // [N,64]
    int N)
{
    const int lane = threadIdx.x & 63;
    const int wib  = threadIdx.x >> 6;
    const int n    = blockIdx.x * 4 + wib;
    if (n >= N) return;

    const unsigned start = offs[n];
    const unsigned end   = offs[n + 1];
    float acc = 0.f;
    for (unsigned k = start; k < end; k += 64) {
        const unsigned rem = end - k;
        const int m = rem < 64u ? (int)rem : 64;
        int2 p = make_int2(0, 0);
        if (lane < m) p = pairs[k + lane];          // coalesced chunk read
        for (int j = 0; j < m; ++j) {
            const int   s  = __shfl(p.x, j);
            const float sc = __int_as_float(__shfl(p.y, j));
            acc += sc * weight[(long long)s * 64 + lane];  // coalesced 256B row
        }
    }
    out[(long long)n * 64 + lane] = acc;            // single row store
}

// ---------------- fallback: round-1 edge-atomic kernel ----------------
__global__ __launch_bounds__(256) void gcmc_edge_kernel(
    const float* __restrict__ weight,
    const float* __restrict__ ps_w,
    const float* __restrict__ review_feat,
    const float* __restrict__ cj,
    const float* __restrict__ ci,
    const int*   __restrict__ src,
    const int*   __restrict__ dst,
    float*       __restrict__ out,
    int E)
{
    const int lane  = threadIdx.x & 63;
    const int wib   = threadIdx.x >> 6;
    const int wave  = blockIdx.x * (blockDim.x >> 6) + wib;
    const int group = lane >> 4;
    const int sub   = lane & 15;

    const int e4 = wave * 4;
    if (e4 >= E) return;

    const int e = e4 + group;
    float x = 0.f;
    if (e < E) {
        const float4 rv = *reinterpret_cast<const float4*>(review_feat + (long long)e * 64 + sub * 4);
        const float4 pw = *reinterpret_cast<const float4*>(ps_w + sub * 4);
        x = rv.x * pw.x + rv.y * pw.y + rv.z * pw.z + rv.w * pw.w;
    }
    x += __shfl_xor(x, 1); x += __shfl_xor(x, 2);
    x += __shfl_xor(x, 4); x += __shfl_xor(x, 8);

    float scale = 0.f;
    int s = 0, d = 0;
    if (e < E) {
        s = src[e]; d = dst[e];
        const float gate = 1.f / (1.f + __expf(-x));
        scale = gate * cj[s] * ci[d];
    }
    #pragma unroll
    for (int k = 0; k < 4; ++k) {
        const int sl = k * 16;
        const float sc = __shfl(scale, sl);
        const int   ss = __shfl(s, sl);
        const int   dd = __shfl(d, sl);
        if (e4 + k < E) {
            const float w = weight[(long long)ss * 64 + lane];
            unsafeAtomicAdd(&out[(long long)dd * 64 + lane], sc * w);
        }
    }
}

extern "C" void kernel_launch(void* const* d_in, const int* in_sizes, int n_in,
                              void* d_out, int out_size, void* d_ws, size_t ws_size,
                              hipStream_t stream) {
    const float* weight      = (const float*)d_in[0];
    const float* ps_w        = (const float*)d_in[1];
    const float* review_feat = (const float*)d_in[2];
    const float* cj          = (const float*)d_in[3];
    const float* ci          = (const float*)d_in[4];
    const int*   src         = (const int*)d_in[5];
    const int*   dst         = (const int*)d_in[6];
    float*       out         = (float*)d_out;

    const int N = in_sizes[3];   // cj has N elements
    const int E = in_sizes[5];

    // workspace layout
    size_t off = 0;
    auto take = [&](size_t bytes) { size_t o = off; off = (off + bytes + 255) & ~(size_t)255; return o; };
    const size_t scale_o  = take((size_t)E * 4);
    const size_t pairs_o  = take((size_t)E * 8);
    const size_t deg_o    = take((size_t)N * 4);
    const size_t offs_o   = take(((size_t)N + 1) * 4);
    const size_t cursor_o = take((size_t)N * 4);

    if (off <= ws_size) {
        char* base = (char*)d_ws;
        float*    scale  = (float*)   (base + scale_o);
        int2*     pairs  = (int2*)    (base + pairs_o);
        unsigned* deg    = (unsigned*)(base + deg_o);
        unsigned* offs   = (unsigned*)(base + offs_o);
        unsigned* cursor = (unsigned*)(base + cursor_o);

        hipMemsetAsync(deg, 0, (size_t)N * 4, stream);
        k1_gate_hist<<<2048, 256, 0, stream>>>(review_feat, ps_w, cj, ci, src, dst,
                                               scale, deg, E);
        k2_scan<<<1, 1024, 0, stream>>>(deg, offs, cursor, N, E);
        k3_scatter<<<2048, 256, 0, stream>>>(src, dst, scale, cursor, pairs, E);
        const int blocks4 = (N + 3) / 4;   // 4 waves (nodes) per block
        k4_gather<<<blocks4, 256, 0, stream>>>(weight, offs, pairs, out, N);
    } else {
        // fallback: round-1 atomic scatter
        hipMemsetAsync(out, 0, (size_t)out_size * sizeof(float), stream);
        const int waves  = (E + 3) / 4;
        const int blocks = (waves + 3) / 4;
        gcmc_edge_kernel<<<blocks, 256, 0, stream>>>(
            weight, ps_w, review_feat, cj, ci, src, dst, out, E);
    }
}

// Round 3
// 560.318 us; speedup vs baseline: 1.6811x; 1.6811x over previous
//
#include <hip/hip_runtime.h>

// out[n,:] = ci[n] * sum_{e: dst[e]==n} sigmoid(<review_feat[e,:], ps_w>) * cj[src[e]] * weight[src[e],:]
//
// Round-2 lesson: CSR beat atomics structurally but the implementation was
// pass-heavy and the single-block scan was uncoalesced. Round 3:
//   kA : deg histogram from dst only              (12.8 MB)
//   kB1: per-4096-tile coalesced LDS scan         (tiny)
//   kB2: scan of 25 tile totals (1 thread)        (tiny)
//   kB3: add tile offsets, emit cursor            (tiny)
//   kC : FUSED gate + scatter (src,scale) pairs   (819 MB stream = the floor)
//   kD : gather, 4 nodes/wave, float4 lanes, single row store, no atomics
// No out memset needed (kD writes every row exactly once).

#define TILE_LOG 12
#define TILE (1 << TILE_LOG)   // 4096 elems per scan tile

// ---------------- kA: degree histogram ----------------
__global__ __launch_bounds__(256) void kA_hist(
    const int* __restrict__ dst, unsigned* __restrict__ deg, int E)
{
    const long long stride = (long long)gridDim.x * blockDim.x;
    for (long long e = (long long)blockIdx.x * blockDim.x + threadIdx.x; e < E; e += stride)
        atomicAdd(&deg[dst[e]], 1u);
}

// ---------------- kB1: per-tile exclusive scan (coalesced) ----------------
__global__ __launch_bounds__(1024) void kB1_tile_scan(
    const unsigned* __restrict__ deg,      // [N]
    unsigned*       __restrict__ offs,     // [N] tile-local exclusive scan
    unsigned*       __restrict__ tilesum,  // [ntiles]
    int N)
{
    __shared__ unsigned lds[TILE];
    __shared__ unsigned sums[1024];
    const int t = threadIdx.x;
    const int base = blockIdx.x << TILE_LOG;

    #pragma unroll
    for (int i = 0; i < 4; ++i) {
        const int idx = base + t + i * 1024;
        lds[t + i * 1024] = (idx < N) ? deg[idx] : 0u;   // coalesced
    }
    __syncthreads();

    // per-thread sum of its contiguous 4 (LDS random access is fine)
    unsigned s = lds[4 * t] + lds[4 * t + 1] + lds[4 * t + 2] + lds[4 * t + 3];
    sums[t] = s;
    __syncthreads();
    // Hillis-Steele inclusive scan over 1024 thread sums
    for (int off = 1; off < 1024; off <<= 1) {
        const unsigned v = (t >= off) ? sums[t - off] : 0u;
        __syncthreads();
        sums[t] += v;
        __syncthreads();
    }
    unsigned run = sums[t] - s;   // exclusive prefix for this thread's chunk
    #pragma unroll
    for (int i = 0; i < 4; ++i) {
        const unsigned tmp = lds[4 * t + i];
        lds[4 * t + i] = run;
        run += tmp;
    }
    __syncthreads();
    #pragma unroll
    for (int i = 0; i < 4; ++i) {
        const int idx = base + t + i * 1024;
        if (idx < N) offs[idx] = lds[t + i * 1024];      // coalesced
    }
    if (t == 1023) tilesum[blockIdx.x] = sums[1023];     // tile total
}

// ---------------- kB2: scan tile totals (trivial size) ----------------
__global__ void kB2_scan_tiles(
    unsigned* __restrict__ tilesum,  // in: totals, out unchanged
    unsigned* __restrict__ tileoff,  // out: exclusive
    unsigned* __restrict__ offs,     // offs[N] = E
    int ntiles, int N)
{
    if (threadIdx.x == 0 && blockIdx.x == 0) {
        unsigned run = 0;
        for (int b = 0; b < ntiles; ++b) {
            tileoff[b] = run;
            run += tilesum[b];
        }
        offs[N] = run;   // == E
    }
}

// ---------------- kB3: globalize offsets, emit cursor ----------------
__global__ __launch_bounds__(256) void kB3_add_offs(
    unsigned* __restrict__ offs,
    unsigned* __restrict__ cursor,
    const unsigned* __restrict__ tileoff,
    int N)
{
    const long long stride = (long long)gridDim.x * blockDim.x;
    for (long long i = (long long)blockIdx.x * blockDim.x + threadIdx.x; i < N; i += stride) {
        const unsigned o = offs[i] + tileoff[i >> TILE_LOG];
        offs[i] = o;
        cursor[i] = o;
    }
}

// ---------------- kC: fused gate + CSR scatter ----------------
__global__ __launch_bounds__(256) void kC_gate_scatter(
    const float* __restrict__ review_feat,  // [E,64]
    const float* __restrict__ ps_w,         // [64]
    const float* __restrict__ cj,           // [N]
    const float* __restrict__ ci,           // [N]
    const int*   __restrict__ src,          // [E]
    const int*   __restrict__ dst,          // [E]
    unsigned*    __restrict__ cursor,       // [N]
    int2*        __restrict__ pairs,        // [E] (src, scale-bits)
    int E)
{
    const int lane  = threadIdx.x & 63;
    const int wib   = threadIdx.x >> 6;
    const int group = lane >> 4;   // which of the wave's 4 edges
    const int sub   = lane & 15;   // float4 chunk within the 64-row
    const float4 pw = *reinterpret_cast<const float4*>(ps_w + sub * 4);

    const long long nwaves = (long long)gridDim.x * 4;
    for (long long w = (long long)blockIdx.x * 4 + wib; w * 4 < E; w += nwaves) {
        const long long e = w * 4 + group;
        float x = 0.f;
        if (e < E) {
            const float4 rv = *reinterpret_cast<const float4*>(review_feat + e * 64 + sub * 4);
            x = rv.x * pw.x + rv.y * pw.y + rv.z * pw.z + rv.w * pw.w;
        }
        x += __shfl_xor(x, 1);
        x += __shfl_xor(x, 2);
        x += __shfl_xor(x, 4);
        x += __shfl_xor(x, 8);
        if (sub == 0 && e < E) {
            const int s = src[e];
            const int d = dst[e];
            const float gate = 1.f / (1.f + __expf(-x));
            const float sc = gate * cj[s] * ci[d];     // ci[dst] folded in
            const unsigned pos = atomicAdd(&cursor[d], 1u);
            pairs[pos] = make_int2(s, __float_as_int(sc));
        }
    }
}

// ---------------- kD: gather-reduce, 4 nodes per wave ----------------
__global__ __launch_bounds__(256) void kD_gather(
    const float*    __restrict__ weight,  // [N,64]
    const unsigned* __restrict__ offs,    // [N+1]
    const int2*     __restrict__ pairs,   // [E]
    float*          __restrict__ out,     // [N,64]
    int N)
{
    const int lane  = threadIdx.x & 63;
    const int wib   = threadIdx.x >> 6;
    const int group = lane >> 4;   // node within wave
    const int sub   = lane & 15;   // float4 chunk of the row

    const long long wave = (long long)blockIdx.x * 4 + wib;
    const long long n = wave * 4 + group;
    if (n >= N) {
        return;   // whole 16-lane group out of range; wave still coherent enough
    }

    const unsigned start = offs[n];
    const unsigned cnt   = offs[n + 1] - start;

    float4 acc = make_float4(0.f, 0.f, 0.f, 0.f);
    for (unsigned j = 0; __any((int)(j < cnt)); ++j) {
        if (j < cnt) {
            const int2 p = pairs[start + j];              // 16 lanes same addr (broadcast)
            const float sc = __int_as_float(p.y);
            const float4 w = *reinterpret_cast<const float4*>(
                weight + (long long)p.x * 64 + sub * 4);  // 4 rows per wave instr
            acc.x += sc * w.x;
            acc.y += sc * w.y;
            acc.z += sc * w.z;
            acc.w += sc * w.w;
        }
    }
    *reinterpret_cast<float4*>(out + n * 64 + sub * 4) = acc;
}

extern "C" void kernel_launch(void* const* d_in, const int* in_sizes, int n_in,
                              void* d_out, int out_size, void* d_ws, size_t ws_size,
                              hipStream_t stream) {
    const float* weight      = (const float*)d_in[0];
    const float* ps_w        = (const float*)d_in[1];
    const float* review_feat = (const float*)d_in[2];
    const float* cj          = (const float*)d_in[3];
    const float* ci          = (const float*)d_in[4];
    const int*   src         = (const int*)d_in[5];
    const int*   dst         = (const int*)d_in[6];
    float*       out         = (float*)d_out;

    const int N = in_sizes[3];
    const int E = in_sizes[5];
    const int ntiles = (N + TILE - 1) / TILE;

    // workspace layout
    size_t off = 0;
    auto take = [&](size_t bytes) { size_t o = off; off = (off + bytes + 255) & ~(size_t)255; return o; };
    const size_t pairs_o   = take((size_t)E * 8);
    const size_t deg_o     = take((size_t)N * 4);
    const size_t offs_o    = take(((size_t)N + 1) * 4);
    const size_t cursor_o  = take((size_t)N * 4);
    const size_t tilesum_o = take((size_t)ntiles * 4);
    const size_t tileoff_o = take((size_t)ntiles * 4);

    char* base = (char*)d_ws;
    int2*     pairs   = (int2*)    (base + pairs_o);
    unsigned* deg     = (unsigned*)(base + deg_o);
    unsigned* offs    = (unsigned*)(base + offs_o);
    unsigned* cursor  = (unsigned*)(base + cursor_o);
    unsigned* tilesum = (unsigned*)(base + tilesum_o);
    unsigned* tileoff = (unsigned*)(base + tileoff_o);

    hipMemsetAsync(deg, 0, (size_t)N * 4, stream);
    kA_hist<<<1024, 256, 0, stream>>>(dst, deg, E);
    kB1_tile_scan<<<ntiles, 1024, 0, stream>>>(deg, offs, tilesum, N);
    kB2_scan_tiles<<<1, 64, 0, stream>>>(tilesum, tileoff, offs, ntiles, N);
    kB3_add_offs<<<256, 256, 0, stream>>>(offs, cursor, tileoff, N);
    kC_gate_scatter<<<2048, 256, 0, stream>>>(review_feat, ps_w, cj, ci, src, dst,
                                              cursor, pairs, E);
    const int blocksD = (N + 15) / 16;   // 16 nodes per block (4 waves x 4 nodes)
    kD_gather<<<blocksD, 256, 0, stream>>>(weight, offs, pairs, out, N);
}

// Round 4
// 541.591 us; speedup vs baseline: 1.7392x; 1.0346x over previous
//
#include <hip/hip_runtime.h>

// out[n,:] = ci[n] * sum_{e: dst[e]==n} sigmoid(<review_feat[e,:], ps_w>) * cj[src[e]] * weight[src[e],:]
//
// Round-3 lesson: the only fills in the timed graph were our 400KB
// hipMemsetAsync(deg), and those dispatches showed ~495us each in rocprof
// (either real cost or an artifact hiding our kernels from top-5). Round 4:
//   kZ : zero deg ourselves (grid-stride store, ~3us) -- NO hipMemsetAsync
//   kA : deg histogram from dst                        (12.8 MB)
//   kB1/kB2/kB3: two-level coalesced scan              (tiny)
//   kC : fused gate + CSR scatter (src,scale) pairs    (819 MB stream floor)
//   kD : gather; 4 nodes/wave; pairs loaded 16-at-a-time coalesced per group,
//        broadcast via intra-group shfl; float4 weight rows (1KB/wave-instr);
//        predicated tails; single row store; no atomics on out.

#define TILE_LOG 12
#define TILE (1 << TILE_LOG)   // 4096 elems per scan tile

// ---------------- kZ: zero the degree array ----------------
__global__ __launch_bounds__(256) void kZ_zero(unsigned* __restrict__ p, int n)
{
    const int i = blockIdx.x * 256 + threadIdx.x;
    if (i < n) p[i] = 0u;
}

// ---------------- kA: degree histogram ----------------
__global__ __launch_bounds__(256) void kA_hist(
    const int* __restrict__ dst, unsigned* __restrict__ deg, int E)
{
    const long long stride = (long long)gridDim.x * blockDim.x;
    for (long long e = (long long)blockIdx.x * blockDim.x + threadIdx.x; e < E; e += stride)
        atomicAdd(&deg[dst[e]], 1u);
}

// ---------------- kB1: per-tile exclusive scan (coalesced) ----------------
__global__ __launch_bounds__(1024) void kB1_tile_scan(
    const unsigned* __restrict__ deg,      // [N]
    unsigned*       __restrict__ offs,     // [N] tile-local exclusive scan
    unsigned*       __restrict__ tilesum,  // [ntiles]
    int N)
{
    __shared__ unsigned lds[TILE];
    __shared__ unsigned sums[1024];
    const int t = threadIdx.x;
    const int base = blockIdx.x << TILE_LOG;

    #pragma unroll
    for (int i = 0; i < 4; ++i) {
        const int idx = base + t + i * 1024;
        lds[t + i * 1024] = (idx < N) ? deg[idx] : 0u;   // coalesced
    }
    __syncthreads();

    unsigned s = lds[4 * t] + lds[4 * t + 1] + lds[4 * t + 2] + lds[4 * t + 3];
    sums[t] = s;
    __syncthreads();
    for (int off = 1; off < 1024; off <<= 1) {
        const unsigned v = (t >= off) ? sums[t - off] : 0u;
        __syncthreads();
        sums[t] += v;
        __syncthreads();
    }
    unsigned run = sums[t] - s;   // exclusive prefix for this thread's chunk
    #pragma unroll
    for (int i = 0; i < 4; ++i) {
        const unsigned tmp = lds[4 * t + i];
        lds[4 * t + i] = run;
        run += tmp;
    }
    __syncthreads();
    #pragma unroll
    for (int i = 0; i < 4; ++i) {
        const int idx = base + t + i * 1024;
        if (idx < N) offs[idx] = lds[t + i * 1024];      // coalesced
    }
    if (t == 1023) tilesum[blockIdx.x] = sums[1023];
}

// ---------------- kB2: scan tile totals (trivial size) ----------------
__global__ void kB2_scan_tiles(
    const unsigned* __restrict__ tilesum,
    unsigned* __restrict__ tileoff,
    unsigned* __restrict__ offs,     // offs[N] = E
    int ntiles, int N)
{
    if (threadIdx.x == 0 && blockIdx.x == 0) {
        unsigned run = 0;
        for (int b = 0; b < ntiles; ++b) {
            tileoff[b] = run;
            run += tilesum[b];
        }
        offs[N] = run;   // == E
    }
}

// ---------------- kB3: globalize offsets, emit cursor ----------------
__global__ __launch_bounds__(256) void kB3_add_offs(
    unsigned* __restrict__ offs,
    unsigned* __restrict__ cursor,
    const unsigned* __restrict__ tileoff,
    int N)
{
    const long long stride = (long long)gridDim.x * blockDim.x;
    for (long long i = (long long)blockIdx.x * blockDim.x + threadIdx.x; i < N; i += stride) {
        const unsigned o = offs[i] + tileoff[i >> TILE_LOG];
        offs[i] = o;
        cursor[i] = o;
    }
}

// ---------------- kC: fused gate + CSR scatter ----------------
__global__ __launch_bounds__(256) void kC_gate_scatter(
    const float* __restrict__ review_feat,  // [E,64]
    const float* __restrict__ ps_w,         // [64]
    const float* __restrict__ cj,           // [N]
    const float* __restrict__ ci,           // [N]
    const int*   __restrict__ src,          // [E]
    const int*   __restrict__ dst,          // [E]
    unsigned*    __restrict__ cursor,       // [N]
    int2*        __restrict__ pairs,        // [E] (src, scale-bits)
    int E)
{
    const int lane  = threadIdx.x & 63;
    const int wib   = threadIdx.x >> 6;
    const int group = lane >> 4;
    const int sub   = lane & 15;
    const float4 pw = *reinterpret_cast<const float4*>(ps_w + sub * 4);

    const long long nwaves = (long long)gridDim.x * 4;
    for (long long w = (long long)blockIdx.x * 4 + wib; w * 4 < E; w += nwaves) {
        const long long e = w * 4 + group;
        float x = 0.f;
        if (e < E) {
            const float4 rv = *reinterpret_cast<const float4*>(review_feat + e * 64 + sub * 4);
            x = rv.x * pw.x + rv.y * pw.y + rv.z * pw.z + rv.w * pw.w;
        }
        x += __shfl_xor(x, 1);
        x += __shfl_xor(x, 2);
        x += __shfl_xor(x, 4);
        x += __shfl_xor(x, 8);
        if (sub == 0 && e < E) {
            const int s = src[e];
            const int d = dst[e];
            const float gate = 1.f / (1.f + __expf(-x));
            const float sc = gate * cj[s] * ci[d];     // ci[dst] folded in
            const unsigned pos = atomicAdd(&cursor[d], 1u);
            pairs[pos] = make_int2(s, __float_as_int(sc));
        }
    }
}

// ---------------- kD: gather-reduce, 4 nodes/wave, chunked pair loads ----------------
__global__ __launch_bounds__(256) void kD_gather(
    const float*    __restrict__ weight,  // [N,64]
    const unsigned* __restrict__ offs,    // [N+1]
    const int2*     __restrict__ pairs,   // [E]
    float*          __restrict__ out,     // [N,64]
    int N)
{
    const int lane  = threadIdx.x & 63;
    const int wib   = threadIdx.x >> 6;
    const int group = lane >> 4;   // node within wave
    const int sub   = lane & 15;   // float4 chunk of the row

    const long long n = ((long long)blockIdx.x * 4 + wib) * 4 + group;
    const bool valid = (n < N);

    unsigned start = 0, cnt = 0;
    if (valid) {
        start = offs[n];
        cnt   = offs[n + 1] - start;
    }

    float4 acc = make_float4(0.f, 0.f, 0.f, 0.f);
    for (unsigned k0 = 0; __any((int)(k0 < cnt)); k0 += 16) {
        // coalesced: 16 lanes of the group load 16 consecutive pairs (128B)
        int2 p = make_int2(0, 0);
        if (k0 + sub < cnt) p = pairs[start + k0 + sub];

        int m = (int)cnt - (int)k0;          // group-uniform
        if (m > 16) m = 16;
        for (int j = 0; j < m; ++j) {        // m <= 0 -> group idles (predicated)
            const int   s  = __shfl(p.x, (group << 4) + j);
            const float sc = __int_as_float(__shfl(p.y, (group << 4) + j));
            const float4 w = *reinterpret_cast<const float4*>(
                weight + (long long)s * 64 + sub * 4);   // 4 rows/wave-instr = 1KB
            acc.x += sc * w.x;
            acc.y += sc * w.y;
            acc.z += sc * w.z;
            acc.w += sc * w.w;
        }
    }
    if (valid)
        *reinterpret_cast<float4*>(out + n * 64 + sub * 4) = acc;
}

extern "C" void kernel_launch(void* const* d_in, const int* in_sizes, int n_in,
                              void* d_out, int out_size, void* d_ws, size_t ws_size,
                              hipStream_t stream) {
    const float* weight      = (const float*)d_in[0];
    const float* ps_w        = (const float*)d_in[1];
    const float* review_feat = (const float*)d_in[2];
    const float* cj          = (const float*)d_in[3];
    const float* ci          = (const float*)d_in[4];
    const int*   src         = (const int*)d_in[5];
    const int*   dst         = (const int*)d_in[6];
    float*       out         = (float*)d_out;

    const int N = in_sizes[3];
    const int E = in_sizes[5];
    const int ntiles = (N + TILE - 1) / TILE;

    size_t off = 0;
    auto take = [&](size_t bytes) { size_t o = off; off = (off + bytes + 255) & ~(size_t)255; return o; };
    const size_t pairs_o   = take((size_t)E * 8);
    const size_t deg_o     = take((size_t)N * 4);
    const size_t offs_o    = take(((size_t)N + 1) * 4);
    const size_t cursor_o  = take((size_t)N * 4);
    const size_t tilesum_o = take((size_t)ntiles * 4);
    const size_t tileoff_o = take((size_t)ntiles * 4);

    char* base = (char*)d_ws;
    int2*     pairs   = (int2*)    (base + pairs_o);
    unsigned* deg     = (unsigned*)(base + deg_o);
    unsigned* offs    = (unsigned*)(base + offs_o);
    unsigned* cursor  = (unsigned*)(base + cursor_o);
    unsigned* tilesum = (unsigned*)(base + tilesum_o);
    unsigned* tileoff = (unsigned*)(base + tileoff_o);

    kZ_zero<<<(N + 255) / 256, 256, 0, stream>>>(deg, N);
    kA_hist<<<1024, 256, 0, stream>>>(dst, deg, E);
    kB1_tile_scan<<<ntiles, 1024, 0, stream>>>(deg, offs, tilesum, N);
    kB2_scan_tiles<<<1, 64, 0, stream>>>(tilesum, tileoff, offs, ntiles, N);
    kB3_add_offs<<<256, 256, 0, stream>>>(offs, cursor, tileoff, N);
    kC_gate_scatter<<<2048, 256, 0, stream>>>(review_feat, ps_w, cj, ci, src, dst,
                                              cursor, pairs, E);
    const int blocksD = (N + 15) / 16;   // 16 nodes per block (4 waves x 4 nodes)
    kD_gather<<<blocksD, 256, 0, stream>>>(weight, offs, pairs, out, N);
}